// Round 8
// baseline (4676.179 us; speedup 1.0000x reference)
//
#include <hip/hip_runtime.h>
#include <hip/hip_bf16.h>

#define TT 1000
#define HH 512
#define HH2 1024
#define DT_ 0.01f
// sqrt(2*DT*SIGMA_RECUR^2), sqrt(2*DT*SIGMA_INPUT^2)
#define PH_SCALE 7.0710678118654745e-4f
#define PI_SCALE 7.0710678118654745e-3f

typedef short s16x8 __attribute__((ext_vector_type(8)));
typedef float f32x4 __attribute__((ext_vector_type(4)));
typedef unsigned u32x4 __attribute__((ext_vector_type(4)));

#define SIGN32  0x80008000u
#define STRIP32 0x7fff7fffu

static __device__ __forceinline__ unsigned short bf16_bits(float f) {
    union { __hip_bfloat16 h; unsigned short u; } b; b.h = __float2bfloat16(f); return b.u;
}
// generation tag for h[t]: 2 bits, period 4; same-slot reuse distance 2 -> always
// differs. End-of-run slots hold tag 3, first-run 0xAA poison reads tag 3, while
// t=0/1 expect tag 0 -> stale data can never satisfy a poll. (R6/R7-proven.)
static __device__ __forceinline__ unsigned pat32(int t) {
    const unsigned tg = ((unsigned)t >> 1) & 3u;
    return ((tg & 1u) << 15) | ((tg & 2u) << 30);
}

// Persistent RNN. Grid: 32 blocks x 512 threads (8 waves). Group = 8 blocks
// owning batch rows [16g, 16g+16); block covers 128 cols (8 waves x 16), wave
// computes a 16x16 C tile. h exchange: relaxed agent-scope stores with
// generation tags embedded in the sign bits of h (h>=0); consumers' cooperative
// stage loads (global_load_dwordx4 sc0 sc1, 4 chunks/thread) poll the data
// itself, strip tags, and share the tile across 8 waves via XOR-swizzled LDS.
// No fences, no counters, no barrier-over-memory. Deadlock-free: a wave only
// waits on data its producers unconditionally publish.
__global__ __launch_bounds__(512, 2) void rnn_persistent(
    const float* __restrict__ inp, const float* __restrict__ hn,
    const float* __restrict__ x0g, const float* __restrict__ inhib,
    const float* __restrict__ ph, const float* __restrict__ pig,
    const float* __restrict__ s2s, const float* __restrict__ a2a,
    const float* __restrict__ a2s, const float* __restrict__ s2a,
    const float* __restrict__ iw,
    float* __restrict__ rnn_out, float* __restrict__ x_out,
    unsigned* __restrict__ hbuf)         // [2][64][512] u32 (packed tagged bf16 pairs)
{
    const int tid  = threadIdx.x;
    const int wid  = tid >> 6;           // wave 0..7
    const int lane = tid & 63;
    const int b    = blockIdx.x;         // 0..31
    const int g    = b >> 3;             // row group (batch rows 16g..16g+16)
    const int qb   = b & 7;              // block within group
    const int l15  = lane & 15;
    const int lq   = lane >> 4;
    const int g16  = g * 16;
    const int icol = (qb * 8 + wid) * 16 + l15;   // output column (= W row)

    __shared__ __align__(16) unsigned short hlds[16 * 1024];  // 32 KB swizzled tile

    // ---- publish h0 FIRST (cheap; peers' t=0 polls succeed early) ----
    {
        float h0v[4];
        #pragma unroll
        for (int r = 0; r < 4; ++r)
            h0v[r] = hn[(size_t)(g16 + lq * 4 + r) * HH2 + icol];
        float prr[4];
        #pragma unroll
        for (int r = 0; r < 4; ++r) prr[r] = __shfl_xor(h0v[r], 1);
        if (!(l15 & 1)) {
            const unsigned p0 = pat32(0);
            #pragma unroll
            for (int r = 0; r < 4; ++r) {
                const unsigned val = (((unsigned)bf16_bits(h0v[r]) |
                                       ((unsigned)bf16_bits(prr[r]) << 16)) & STRIP32);
                __hip_atomic_store(hbuf + (size_t)(g16 + lq * 4 + r) * 512 + (icol >> 1),
                                   val | p0, __ATOMIC_RELAXED, __HIP_MEMORY_SCOPE_AGENT);
            }
        }
    }

    // ---- W fragments in registers (one-time, f32 -> bf16) ----
    s16x8 wfr[32];
    #pragma unroll
    for (int kc = 0; kc < 32; ++kc) {
        const int j = kc * 32 + lq * 8;
        const float* src;
        if (icol < HH) src = (j < HH) ? (s2s + (size_t)icol * HH + j)
                                      : (a2s + (size_t)icol * HH + (j - HH));
        else           src = (j < HH) ? (s2a + (size_t)(icol - HH) * HH + j)
                                      : (a2a + (size_t)(icol - HH) * HH + (j - HH));
        const float4 f0 = *(const float4*)(src);
        const float4 f1 = *(const float4*)(src + 4);
        union { s16x8 vv; unsigned short us[8]; } u;
        u.us[0] = bf16_bits(f0.x); u.us[1] = bf16_bits(f0.y);
        u.us[2] = bf16_bits(f0.z); u.us[3] = bf16_bits(f0.w);
        u.us[4] = bf16_bits(f1.x); u.us[5] = bf16_bits(f1.y);
        u.us[6] = bf16_bits(f1.z); u.us[7] = bf16_bits(f1.w);
        wfr[kc] = u.vv;
    }

    // ---- register-resident epilogue state (rows lq*4+r of the group tile) ----
    const bool isStr = (icol < HH);
    float iw0 = 0.f, iw1 = 0.f, iw2 = 0.f, iw3 = 0.f;
    if (isStr) {
        iw0 = iw[icol]; iw1 = iw[HH2 + icol];
        iw2 = iw[2 * HH2 + icol]; iw3 = iw[3 * HH2 + icol];
    }
    float xr[4], inh[4];
    float4 ipf[4];
    #pragma unroll
    for (int r = 0; r < 4; ++r) {
        const int bi = g16 + lq * 4 + r;
        xr[r]  = x0g[(size_t)bi * HH2 + icol];
        inh[r] = inhib[(size_t)bi * HH2 + icol];
        ipf[r] = *(const float4*)(inp + ((size_t)bi * TT + 0) * 4);
    }
    float phv = ph[0], piv = pig[0];

    #pragma unroll 1
    for (int t = 0; t < TT; ++t) {
        const unsigned* srcs = hbuf + (size_t)(t & 1) * 32768 + (size_t)g16 * 512;
        const unsigned p32 = pat32(t);

        // protect LDS from previous iteration's readers
        __syncthreads();

        // ---- cooperative poll+stage: 4 x 16B chunks per thread ----
        {
            u32x4 c[4];
            #pragma unroll
            for (int rd = 0; rd < 4; ++rd) {
                const int gch = tid + rd * 512;            // chunk id [0,2048)
                const int row = gch >> 7, c16 = gch & 127;
                const unsigned* p = srcs + row * 512 + c16 * 4;
                asm volatile("global_load_dwordx4 %0, %1, off sc0 sc1"
                             : "=v"(c[rd]) : "v"(p) : "memory");
            }
            asm volatile("s_waitcnt vmcnt(0)" ::: "memory");
            unsigned fm = 0u;
            #pragma unroll
            for (int rd = 0; rd < 4; ++rd) {
                const unsigned y = ((c[rd][0] ^ p32) | (c[rd][1] ^ p32) |
                                    (c[rd][2] ^ p32) | (c[rd][3] ^ p32)) & SIGN32;
                if (y) fm |= 1u << rd;
            }
            while (fm) {
                #pragma unroll
                for (int rd = 0; rd < 4; ++rd) {
                    if (fm & (1u << rd)) {
                        const int gch = tid + rd * 512;
                        const int row = gch >> 7, c16 = gch & 127;
                        const unsigned* p = srcs + row * 512 + c16 * 4;
                        asm volatile("global_load_dwordx4 %0, %1, off sc0 sc1"
                                     : "=v"(c[rd]) : "v"(p) : "memory");
                    }
                }
                asm volatile("s_waitcnt vmcnt(0)" ::: "memory");
                #pragma unroll
                for (int rd = 0; rd < 4; ++rd) {
                    if (fm & (1u << rd)) {
                        const unsigned y = ((c[rd][0] ^ p32) | (c[rd][1] ^ p32) |
                                            (c[rd][2] ^ p32) | (c[rd][3] ^ p32)) & SIGN32;
                        if (!y) fm &= ~(1u << rd);
                    }
                }
            }
            #pragma unroll
            for (int rd = 0; rd < 4; ++rd) {
                const int gch = tid + rd * 512;
                const int row = gch >> 7, c16 = gch & 127;
                u32x4 s;
                s[0] = c[rd][0] & STRIP32; s[1] = c[rd][1] & STRIP32;
                s[2] = c[rd][2] & STRIP32; s[3] = c[rd][3] & STRIP32;
                *(u32x4*)((char*)hlds + row * 2048 + ((c16 ^ (row & 7)) * 16)) = s;
            }
        }
        __syncthreads();

        // ---- MFMA: C rows lq*4+r, col icol, K=1024 from swizzled LDS ----
        f32x4 acc[4] = {{0,0,0,0},{0,0,0,0},{0,0,0,0},{0,0,0,0}};
        const char* arow = (const char*)hlds + l15 * 2048;
        #pragma unroll
        for (int kc = 0; kc < 32; ++kc) {
            s16x8 a0 = *(const s16x8*)(arow + (((kc << 2 | lq) ^ (l15 & 7)) * 16));
            acc[kc & 3] = __builtin_amdgcn_mfma_f32_16x16x32_bf16(a0, wfr[kc], acc[kc & 3], 0, 0, 0);
        }

        // ---- epilogue ----
        const float phs = PH_SCALE * phv;
        const float pis = PI_SCALE * piv;
        float xn_[4], hv_[4];
        #pragma unroll
        for (int r = 0; r < 4; ++r) {
            const float rec = acc[0][r] + acc[1][r] + acc[2][r] + acc[3][r];
            float drive = 0.f;
            if (isStr) drive = (ipf[r].x + pis) * iw0 + (ipf[r].y + pis) * iw1 +
                               (ipf[r].z + pis) * iw2 + (ipf[r].w + pis) * iw3;
            const float xp = xr[r];
            const float xn = xp + DT_ * (-xp + rec + drive + inh[r]) + phs;
            const float hv = fmaxf(xn, 0.f);
            xr[r] = xn; xn_[r] = xn; hv_[r] = hv;
        }

        // ---- publish h[t+1], fire-and-forget (skip at t=TT-1: unused; keeps
        //      replay tag-safety: end-state tags never equal t=0/1 expectations) ----
        if (t + 1 < TT) {
            unsigned* nxt = hbuf + (size_t)((t + 1) & 1) * 32768;
            const unsigned pn = pat32(t + 1);
            float prr[4];
            #pragma unroll
            for (int r = 0; r < 4; ++r) prr[r] = __shfl_xor(hv_[r], 1);
            if (!(l15 & 1)) {
                #pragma unroll
                for (int r = 0; r < 4; ++r) {
                    const unsigned val = (((unsigned)bf16_bits(hv_[r]) |
                                           ((unsigned)bf16_bits(prr[r]) << 16)) & STRIP32);
                    __hip_atomic_store(nxt + (size_t)(g16 + lq * 4 + r) * 512 + (icol >> 1),
                                       val | pn, __ATOMIC_RELAXED, __HIP_MEMORY_SCOPE_AGENT);
                }
            }
        }

        // ---- off-critical-path: history stores + next-step input prefetch ----
        #pragma unroll
        for (int r = 0; r < 4; ++r) {
            const int bi = g16 + lq * 4 + r;
            const size_t o = ((size_t)bi * TT + t) * HH2 + icol;
            __builtin_nontemporal_store(hv_[r], rnn_out + o);
            __builtin_nontemporal_store(xn_[r], x_out + o);
        }
        const int tn = (t + 1 < TT) ? (t + 1) : t;
        #pragma unroll
        for (int r = 0; r < 4; ++r)
            ipf[r] = *(const float4*)(inp + ((size_t)(g16 + lq * 4 + r) * TT + tn) * 4);
        phv = ph[tn]; piv = pig[tn];
    }
}

// ---------------- fc1: out[b,t] = dot(rnn_out[b,t,512:1024], fc1_w[512:1024]) + fc1_b ----------------
__global__ __launch_bounds__(256) void fc1_kernel(
    const float* __restrict__ rnn_out, const float* __restrict__ fc1_w,
    const float* __restrict__ fc1_b, float* __restrict__ out)
{
    const int wid = blockIdx.x * 4 + (threadIdx.x >> 6);  // [0, 64000)
    const int lane = threadIdx.x & 63;
    const float* p = rnn_out + (size_t)wid * HH2 + HH + lane * 8;
    const float* w = fc1_w + HH + lane * 8;
    f32x4 v0 = *(const f32x4*)(p);
    f32x4 v1 = *(const f32x4*)(p + 4);
    f32x4 w0 = *(const f32x4*)(w);
    f32x4 w1 = *(const f32x4*)(w + 4);
    float s = v0[0]*w0[0] + v0[1]*w0[1] + v0[2]*w0[2] + v0[3]*w0[3]
            + v1[0]*w1[0] + v1[1]*w1[1] + v1[2]*w1[2] + v1[3]*w1[3];
    #pragma unroll
    for (int off = 32; off; off >>= 1) s += __shfl_xor(s, off);
    if (lane == 0) out[wid] = s + fc1_b[0];
}

// ---------------- last-state extraction ----------------
__global__ __launch_bounds__(256) void last_kernel(
    const float* __restrict__ rnn_out, const float* __restrict__ x_out,
    float* __restrict__ hn_last, float* __restrict__ x_last)
{
    const int idx = blockIdx.x * 256 + threadIdx.x;  // [0, 65536)
    const int b = idx >> 10;
    const int i = idx & 1023;
    const size_t o = ((size_t)b * TT + (TT - 1)) * HH2 + i;
    hn_last[idx] = rnn_out[o];
    x_last[idx]  = x_out[o];
}

extern "C" void kernel_launch(void* const* d_in, const int* in_sizes, int n_in,
                              void* d_out, int out_size, void* d_ws, size_t ws_size,
                              hipStream_t stream) {
    const float* inp   = (const float*)d_in[0];   // [64,1000,4]
    const float* hn    = (const float*)d_in[1];   // [1,64,1024]
    const float* x     = (const float*)d_in[2];   // [1,64,1024]
    const float* inhib = (const float*)d_in[3];   // [64,1024]
    const float* ph    = (const float*)d_in[4];   // [1000]
    const float* pi    = (const float*)d_in[5];   // [1000]
    const float* s2s   = (const float*)d_in[6];   // [512,512]
    const float* a2a   = (const float*)d_in[7];
    const float* a2s   = (const float*)d_in[8];
    const float* s2a   = (const float*)d_in[9];
    const float* iw    = (const float*)d_in[10];  // [4,1024]
    const float* fw    = (const float*)d_in[11];  // [1,1024]
    const float* fb    = (const float*)d_in[12];  // [1]

    // Output tuple layout (floats): out | hn_last | rnn_out | x_last | x_out
    float* out     = (float*)d_out;               // 64000
    float* hn_last = out + 64000;                 // 65536
    float* rnn_out = out + 129536;                // 65,536,000
    float* x_last  = out + 65665536;              // 65536
    float* x_out   = out + 65731072;              // 65,536,000

    // Workspace: hbuf [2][64][512] u32 = 256 KB. No init needed: generation tags
    // self-disambiguate against both 0xAA poison and previous-replay residue.
    unsigned* hbuf = (unsigned*)d_ws;

    rnn_persistent<<<32, 512, 0, stream>>>(inp, hn, x, inhib, ph, pi,
                                           s2s, a2a, a2s, s2a, iw,
                                           rnn_out, x_out, hbuf);
    fc1_kernel<<<16000, 256, 0, stream>>>(rnn_out, fw, fb, out);
    last_kernel<<<256, 256, 0, stream>>>(rnn_out, x_out, hn_last, x_last);
}

// Round 9
// 3167.057 us; speedup vs baseline: 1.4765x; 1.4765x over previous
//
#include <hip/hip_runtime.h>
#include <hip/hip_bf16.h>

#define TT 1000
#define HH 512
#define HH2 1024
#define DT_ 0.01f
// sqrt(2*DT*SIGMA_RECUR^2), sqrt(2*DT*SIGMA_INPUT^2)
#define PH_SCALE 7.0710678118654745e-4f
#define PI_SCALE 7.0710678118654745e-3f

typedef short s16x8 __attribute__((ext_vector_type(8)));
typedef float f32x4 __attribute__((ext_vector_type(4)));
typedef unsigned u32x4 __attribute__((ext_vector_type(4)));

static __device__ __forceinline__ unsigned short bf16_bits(float f) {
    union { __hip_bfloat16 h; unsigned short u; } b; b.h = __float2bfloat16(f); return b.u;
}
// Device-coherent (L3) tag load; sc0 sc1 = bypass L1/L2 (R8-proven op).
static __device__ __forceinline__ unsigned ld_tag(const unsigned* p) {
    unsigned r;
    asm volatile("global_load_dword %0, %1, off sc0 sc1\n\ts_waitcnt vmcnt(0)"
                 : "=v"(r) : "v"(p) : "memory");
    return r;
}

// Persistent RNN. Grid: 64 blocks x 256 threads (4 waves). Group = 16 blocks
// owning batch rows [16g,16g+16); block = 64 cols (4 waves x 16), wave = 16x16
// C tile. Protocol (R3-class, barrier-certified; drains engineered off the
// critical path):
//   publish own tile (agent atomics -> L3) ; history stores PLAIN (L2-ack),
//   issued before the one vmcnt(0) that drains both ; lane0 stores per-WAVE
//   tag (no RMW, no cross-wave sync needed: vmcnt is wave-scope) ; consumers
//   poll 64 wave-tags with 64 lanes + __ballot ; stage = 8 x dwordx4 sc0 sc1
//   into double-buffered swizzled LDS ; ONE __syncthreads per step.
// Deadlock-free: every wave stores its tag unconditionally every step.
// Overwrite-safe: tag>=t+1 from block j implies j passed its stage->MFMA
// barrier for h[t-1], so h[t+1] may overwrite h[t-1]'s slot.
__global__ __launch_bounds__(256, 1) void rnn_persistent(
    const float* __restrict__ inp, const float* __restrict__ hn,
    const float* __restrict__ x0g, const float* __restrict__ inhib,
    const float* __restrict__ ph, const float* __restrict__ pig,
    const float* __restrict__ s2s, const float* __restrict__ a2a,
    const float* __restrict__ a2s, const float* __restrict__ s2a,
    const float* __restrict__ iw,
    float* __restrict__ rnn_out, float* __restrict__ x_out,
    unsigned* __restrict__ hbuf,         // [2][64][512] u32 (packed bf16 pairs)
    unsigned* __restrict__ tagbuf)       // [4][64] u32, 64 B stride (memset 0)
{
    const int tid  = threadIdx.x;
    const int wid  = tid >> 6;
    const int lane = tid & 63;
    const int b    = blockIdx.x;         // 0..63
    const int g    = b >> 4;             // row group (batch rows 16g..16g+16)
    const int qb   = b & 15;             // block within group
    const int l15  = lane & 15;
    const int lq   = lane >> 4;
    const int g16  = g * 16;
    const int icol = (qb * 4 + wid) * 16 + l15;   // output column (= W row)

    __shared__ __align__(16) unsigned short hlds[2][16 * 1024];  // 2 x 32 KB

    unsigned* mytag = tagbuf + (g * 64 + qb * 4 + wid) * 16;

    // ---- publish h0 (per-wave tile) + tag=1 FIRST; W gather after ----
    {
        float h0v[4];
        #pragma unroll
        for (int r = 0; r < 4; ++r)
            h0v[r] = hn[(size_t)(g16 + lq * 4 + r) * HH2 + icol];
        float prr[4];
        #pragma unroll
        for (int r = 0; r < 4; ++r) prr[r] = __shfl_xor(h0v[r], 1);
        if (!(l15 & 1)) {
            #pragma unroll
            for (int r = 0; r < 4; ++r) {
                const unsigned val = (unsigned)bf16_bits(h0v[r]) |
                                     ((unsigned)bf16_bits(prr[r]) << 16);
                __hip_atomic_store(hbuf + (size_t)(g16 + lq * 4 + r) * 512 + (icol >> 1),
                                   val, __ATOMIC_RELAXED, __HIP_MEMORY_SCOPE_AGENT);
            }
        }
        asm volatile("s_waitcnt vmcnt(0)" ::: "memory");   // wave-scope drain
        if (lane == 0)
            __hip_atomic_store(mytag, 1u, __ATOMIC_RELAXED, __HIP_MEMORY_SCOPE_AGENT);
    }

    // ---- W fragments in registers (one-time, f32 -> bf16) ----
    s16x8 wfr[32];
    #pragma unroll
    for (int kc = 0; kc < 32; ++kc) {
        const int j = kc * 32 + lq * 8;
        const float* src;
        if (icol < HH) src = (j < HH) ? (s2s + (size_t)icol * HH + j)
                                      : (a2s + (size_t)icol * HH + (j - HH));
        else           src = (j < HH) ? (s2a + (size_t)(icol - HH) * HH + j)
                                      : (a2a + (size_t)(icol - HH) * HH + (j - HH));
        const float4 f0 = *(const float4*)(src);
        const float4 f1 = *(const float4*)(src + 4);
        union { s16x8 vv; unsigned short us[8]; } u;
        u.us[0] = bf16_bits(f0.x); u.us[1] = bf16_bits(f0.y);
        u.us[2] = bf16_bits(f0.z); u.us[3] = bf16_bits(f0.w);
        u.us[4] = bf16_bits(f1.x); u.us[5] = bf16_bits(f1.y);
        u.us[6] = bf16_bits(f1.z); u.us[7] = bf16_bits(f1.w);
        wfr[kc] = u.vv;
    }

    // ---- register-resident epilogue state (rows lq*4+r of the group tile) ----
    const bool isStr = (icol < HH);
    float iw0 = 0.f, iw1 = 0.f, iw2 = 0.f, iw3 = 0.f;
    if (isStr) {
        iw0 = iw[icol]; iw1 = iw[HH2 + icol];
        iw2 = iw[2 * HH2 + icol]; iw3 = iw[3 * HH2 + icol];
    }
    float xr[4], inh[4];
    float4 ipf[4];
    #pragma unroll
    for (int r = 0; r < 4; ++r) {
        const int bi = g16 + lq * 4 + r;
        xr[r]  = x0g[(size_t)bi * HH2 + icol];
        inh[r] = inhib[(size_t)bi * HH2 + icol];
        ipf[r] = *(const float4*)(inp + ((size_t)bi * TT + 0) * 4);
    }
    float phv = ph[0], piv = pig[0];

    #pragma unroll 1
    for (int t = 0; t < TT; ++t) {
        const unsigned want = (unsigned)(t + 1);

        // ---- poll: 64 lanes x 1 wave-tag each ----
        {
            const unsigned* tp = tagbuf + (g * 64 + lane) * 16;
            unsigned tv = ld_tag(tp);
            while (__ballot(tv < want) != 0ull) {
                if (tv < want) tv = ld_tag(tp);
            }
        }

        // ---- stage tile [16][1024] bf16 -> swizzled LDS buf (8 x 16B/thread) ----
        {
            const unsigned* srcs = hbuf + (size_t)(t & 1) * 32768 + (size_t)g16 * 512;
            char* dst = (char*)hlds[t & 1];
            u32x4 c[8];
            #pragma unroll
            for (int rd = 0; rd < 8; ++rd) {
                const int gch = tid + rd * 256;            // chunk id [0,2048)
                const int row = gch >> 7, c16 = gch & 127;
                const unsigned* p = srcs + row * 512 + c16 * 4;
                asm volatile("global_load_dwordx4 %0, %1, off sc0 sc1"
                             : "=v"(c[rd]) : "v"(p) : "memory");
            }
            asm volatile("s_waitcnt vmcnt(0)" ::: "memory");
            #pragma unroll
            for (int rd = 0; rd < 8; ++rd) {
                const int gch = tid + rd * 256;
                const int row = gch >> 7, c16 = gch & 127;
                *(u32x4*)(dst + row * 2048 + ((c16 ^ (row & 7)) * 16)) = c[rd];
            }
        }
        __syncthreads();   // the ONE barrier: stage complete -> MFMA may read

        // ---- MFMA: C rows lq*4+r, col icol, K=1024 from swizzled LDS ----
        f32x4 acc[4] = {{0,0,0,0},{0,0,0,0},{0,0,0,0},{0,0,0,0}};
        const char* arow = (const char*)hlds[t & 1] + l15 * 2048;
        #pragma unroll
        for (int kc = 0; kc < 32; ++kc) {
            s16x8 a0 = *(const s16x8*)(arow + (((kc << 2 | lq) ^ (l15 & 7)) * 16));
            acc[kc & 3] = __builtin_amdgcn_mfma_f32_16x16x32_bf16(a0, wfr[kc], acc[kc & 3], 0, 0, 0);
        }

        // ---- epilogue ----
        const float phs = PH_SCALE * phv;
        const float pis = PI_SCALE * piv;
        float xn_[4], hv_[4];
        #pragma unroll
        for (int r = 0; r < 4; ++r) {
            const float rec = acc[0][r] + acc[1][r] + acc[2][r] + acc[3][r];
            float drive = 0.f;
            if (isStr) drive = (ipf[r].x + pis) * iw0 + (ipf[r].y + pis) * iw1 +
                               (ipf[r].z + pis) * iw2 + (ipf[r].w + pis) * iw3;
            const float xp = xr[r];
            const float xn = xp + DT_ * (-xp + rec + drive + inh[r]) + phs;
            const float hv = fmaxf(xn, 0.f);
            xr[r] = xn; xn_[r] = xn; hv_[r] = hv;
        }

        // ---- history stores: PLAIN (L2-ack) and BEFORE the drain, so their
        //      latency hides under the publish drain ----
        #pragma unroll
        for (int r = 0; r < 4; ++r) {
            const int bi = g16 + lq * 4 + r;
            const size_t o = ((size_t)bi * TT + t) * HH2 + icol;
            rnn_out[o] = hv_[r];
            x_out[o]   = xn_[r];
        }

        // ---- publish h[t+1] + per-wave tag (skip at t=TT-1: unused) ----
        if (t + 1 < TT) {
            unsigned* nxt = hbuf + (size_t)((t + 1) & 1) * 32768;
            float prr[4];
            #pragma unroll
            for (int r = 0; r < 4; ++r) prr[r] = __shfl_xor(hv_[r], 1);
            if (!(l15 & 1)) {
                #pragma unroll
                for (int r = 0; r < 4; ++r) {
                    const unsigned val = (unsigned)bf16_bits(hv_[r]) |
                                         ((unsigned)bf16_bits(prr[r]) << 16);
                    __hip_atomic_store(nxt + (size_t)(g16 + lq * 4 + r) * 512 + (icol >> 1),
                                       val, __ATOMIC_RELAXED, __HIP_MEMORY_SCOPE_AGENT);
                }
            }
            asm volatile("s_waitcnt vmcnt(0)" ::: "memory");  // drains publish + history
            if (lane == 0)
                __hip_atomic_store(mytag, (unsigned)(t + 2),
                                   __ATOMIC_RELAXED, __HIP_MEMORY_SCOPE_AGENT);
        }

        // ---- off-critical-path: next-step input prefetch ----
        const int tn = (t + 1 < TT) ? (t + 1) : t;
        #pragma unroll
        for (int r = 0; r < 4; ++r)
            ipf[r] = *(const float4*)(inp + ((size_t)(g16 + lq * 4 + r) * TT + tn) * 4);
        phv = ph[tn]; piv = pig[tn];
    }
}

// ---------------- fc1: out[b,t] = dot(rnn_out[b,t,512:1024], fc1_w[512:1024]) + fc1_b ----------------
__global__ __launch_bounds__(256) void fc1_kernel(
    const float* __restrict__ rnn_out, const float* __restrict__ fc1_w,
    const float* __restrict__ fc1_b, float* __restrict__ out)
{
    const int wid = blockIdx.x * 4 + (threadIdx.x >> 6);  // [0, 64000)
    const int lane = threadIdx.x & 63;
    const float* p = rnn_out + (size_t)wid * HH2 + HH + lane * 8;
    const float* w = fc1_w + HH + lane * 8;
    f32x4 v0 = *(const f32x4*)(p);
    f32x4 v1 = *(const f32x4*)(p + 4);
    f32x4 w0 = *(const f32x4*)(w);
    f32x4 w1 = *(const f32x4*)(w + 4);
    float s = v0[0]*w0[0] + v0[1]*w0[1] + v0[2]*w0[2] + v0[3]*w0[3]
            + v1[0]*w1[0] + v1[1]*w1[1] + v1[2]*w1[2] + v1[3]*w1[3];
    #pragma unroll
    for (int off = 32; off; off >>= 1) s += __shfl_xor(s, off);
    if (lane == 0) out[wid] = s + fc1_b[0];
}

// ---------------- last-state extraction ----------------
__global__ __launch_bounds__(256) void last_kernel(
    const float* __restrict__ rnn_out, const float* __restrict__ x_out,
    float* __restrict__ hn_last, float* __restrict__ x_last)
{
    const int idx = blockIdx.x * 256 + threadIdx.x;  // [0, 65536)
    const int b = idx >> 10;
    const int i = idx & 1023;
    const size_t o = ((size_t)b * TT + (TT - 1)) * HH2 + i;
    hn_last[idx] = rnn_out[o];
    x_last[idx]  = x_out[o];
}

extern "C" void kernel_launch(void* const* d_in, const int* in_sizes, int n_in,
                              void* d_out, int out_size, void* d_ws, size_t ws_size,
                              hipStream_t stream) {
    const float* inp   = (const float*)d_in[0];   // [64,1000,4]
    const float* hn    = (const float*)d_in[1];   // [1,64,1024]
    const float* x     = (const float*)d_in[2];   // [1,64,1024]
    const float* inhib = (const float*)d_in[3];   // [64,1024]
    const float* ph    = (const float*)d_in[4];   // [1000]
    const float* pi    = (const float*)d_in[5];   // [1000]
    const float* s2s   = (const float*)d_in[6];   // [512,512]
    const float* a2a   = (const float*)d_in[7];
    const float* a2s   = (const float*)d_in[8];
    const float* s2a   = (const float*)d_in[9];
    const float* iw    = (const float*)d_in[10];  // [4,1024]
    const float* fw    = (const float*)d_in[11];  // [1,1024]
    const float* fb    = (const float*)d_in[12];  // [1]

    // Output tuple layout (floats): out | hn_last | rnn_out | x_last | x_out
    float* out     = (float*)d_out;               // 64000
    float* hn_last = out + 64000;                 // 65536
    float* rnn_out = out + 129536;                // 65,536,000
    float* x_last  = out + 65665536;              // 65536
    float* x_out   = out + 65731072;              // 65,536,000

    // Workspace: tagbuf 16 KB (memset 0 per launch) | hbuf [2][64][512] u32 (256 KB)
    unsigned* tagbuf = (unsigned*)d_ws;
    unsigned* hbuf   = (unsigned*)((char*)d_ws + 16384);

    hipMemsetAsync(tagbuf, 0, 16384, stream);
    rnn_persistent<<<64, 256, 0, stream>>>(inp, hn, x, inhib, ph, pi,
                                           s2s, a2a, a2s, s2a, iw,
                                           rnn_out, x_out, hbuf, tagbuf);
    fc1_kernel<<<16000, 256, 0, stream>>>(rnn_out, fw, fb, out);
    last_kernel<<<256, 256, 0, stream>>>(rnn_out, x_out, hn_last, x_last);
}

// Round 10
// 2904.159 us; speedup vs baseline: 1.6102x; 1.0905x over previous
//
#include <hip/hip_runtime.h>
#include <hip/hip_bf16.h>

#define TT 1000
#define HH 512
#define HH2 1024
#define DT_ 0.01f
// sqrt(2*DT*SIGMA_RECUR^2), sqrt(2*DT*SIGMA_INPUT^2)
#define PH_SCALE 7.0710678118654745e-4f
#define PI_SCALE 7.0710678118654745e-3f

typedef short s16x8 __attribute__((ext_vector_type(8)));
typedef float f32x4 __attribute__((ext_vector_type(4)));
typedef unsigned u32x4 __attribute__((ext_vector_type(4)));

#define SIGN32  0x80008000u
#define STRIP32 0x7fff7fffu

static __device__ __forceinline__ unsigned short bf16_bits(float f) {
    union { __hip_bfloat16 h; unsigned short u; } b; b.h = __float2bfloat16(f); return b.u;
}
// generation tag for h[t]: 2 bits, period 4; same-slot reuse distance 2 -> adjacent
// generations always differ. End-of-run slots hold tag 3 and 0xAA poison reads tag 3,
// while t=0/1 expect tag 0 -> stale data can never satisfy a poll. (R6/R7-proven.)
static __device__ __forceinline__ unsigned pat32(int t) {
    const unsigned tg = ((unsigned)t >> 1) & 3u;
    return ((tg & 1u) << 15) | ((tg & 2u) << 30);
}

// Persistent RNN. Grid: 64 blocks x 256 threads (4 waves). Group = 16 blocks
// owning batch rows [16g,16g+16); block = 64 cols (4 waves x 16), wave = 16x16
// C tile. Protocol: tag-in-data (R6/R7) on the R9 skeleton (dbuf LDS, ONE
// barrier/step, plain history stores overlapped under the stage vmcnt):
//   publish h[t+1] tagged, FIRE-AND-FORGET (no drain, no tag array, no tag
//   store) ; history stores plain (L2-ack) issued right after, their acks
//   overlap the stage loads' L3 latency inside the same vmcnt(0) ; stage =
//   8 x dwordx4 sc0 sc1 per thread with per-chunk tag validation + straggler
//   retries -> the successful round IS the readiness detection (one RTT for
//   poll+stage combined) ; strip signs -> swizzled LDS dbuf ; barrier ; MFMA.
// Deadlock-free: publishes are unconditional; a wave only waits on data its
// producers will publish. Overwrite-safe: gen t+1 is published only after
// tag-matching ALL of gen t, which certifies peers finished reading gen t-1.
__global__ __launch_bounds__(256, 1) void rnn_persistent(
    const float* __restrict__ inp, const float* __restrict__ hn,
    const float* __restrict__ x0g, const float* __restrict__ inhib,
    const float* __restrict__ ph, const float* __restrict__ pig,
    const float* __restrict__ s2s, const float* __restrict__ a2a,
    const float* __restrict__ a2s, const float* __restrict__ s2a,
    const float* __restrict__ iw,
    float* __restrict__ rnn_out, float* __restrict__ x_out,
    unsigned* __restrict__ hbuf)         // [2][64][512] u32 (packed tagged bf16 pairs)
{
    const int tid  = threadIdx.x;
    const int wid  = tid >> 6;
    const int lane = tid & 63;
    const int b    = blockIdx.x;         // 0..63
    const int g    = b >> 4;             // row group (batch rows 16g..16g+16)
    const int qb   = b & 15;             // block within group
    const int l15  = lane & 15;
    const int lq   = lane >> 4;
    const int g16  = g * 16;
    const int icol = (qb * 4 + wid) * 16 + l15;   // output column (= W row)

    __shared__ __align__(16) unsigned short hlds[2][16 * 1024];  // 2 x 32 KB

    // ---- publish h0 FIRST (tag gen 0); peers' t=0 stage can succeed early ----
    {
        float h0v[4];
        #pragma unroll
        for (int r = 0; r < 4; ++r)
            h0v[r] = hn[(size_t)(g16 + lq * 4 + r) * HH2 + icol];
        float prr[4];
        #pragma unroll
        for (int r = 0; r < 4; ++r) prr[r] = __shfl_xor(h0v[r], 1);
        if (!(l15 & 1)) {
            const unsigned p0 = pat32(0);
            #pragma unroll
            for (int r = 0; r < 4; ++r) {
                const unsigned val = (((unsigned)bf16_bits(h0v[r]) |
                                       ((unsigned)bf16_bits(prr[r]) << 16)) & STRIP32);
                __hip_atomic_store(hbuf + (size_t)(g16 + lq * 4 + r) * 512 + (icol >> 1),
                                   val | p0, __ATOMIC_RELAXED, __HIP_MEMORY_SCOPE_AGENT);
            }
        }
    }

    // ---- W fragments in registers (one-time, f32 -> bf16) ----
    s16x8 wfr[32];
    #pragma unroll
    for (int kc = 0; kc < 32; ++kc) {
        const int j = kc * 32 + lq * 8;
        const float* src;
        if (icol < HH) src = (j < HH) ? (s2s + (size_t)icol * HH + j)
                                      : (a2s + (size_t)icol * HH + (j - HH));
        else           src = (j < HH) ? (s2a + (size_t)(icol - HH) * HH + j)
                                      : (a2a + (size_t)(icol - HH) * HH + (j - HH));
        const float4 f0 = *(const float4*)(src);
        const float4 f1 = *(const float4*)(src + 4);
        union { s16x8 vv; unsigned short us[8]; } u;
        u.us[0] = bf16_bits(f0.x); u.us[1] = bf16_bits(f0.y);
        u.us[2] = bf16_bits(f0.z); u.us[3] = bf16_bits(f0.w);
        u.us[4] = bf16_bits(f1.x); u.us[5] = bf16_bits(f1.y);
        u.us[6] = bf16_bits(f1.z); u.us[7] = bf16_bits(f1.w);
        wfr[kc] = u.vv;
    }

    // ---- register-resident epilogue state (rows lq*4+r of the group tile) ----
    const bool isStr = (icol < HH);
    float iw0 = 0.f, iw1 = 0.f, iw2 = 0.f, iw3 = 0.f;
    if (isStr) {
        iw0 = iw[icol]; iw1 = iw[HH2 + icol];
        iw2 = iw[2 * HH2 + icol]; iw3 = iw[3 * HH2 + icol];
    }
    float xr[4], inh[4];
    float4 ipf[4];
    #pragma unroll
    for (int r = 0; r < 4; ++r) {
        const int bi = g16 + lq * 4 + r;
        xr[r]  = x0g[(size_t)bi * HH2 + icol];
        inh[r] = inhib[(size_t)bi * HH2 + icol];
        ipf[r] = *(const float4*)(inp + ((size_t)bi * TT + 0) * 4);
    }
    float phv = ph[0], piv = pig[0];

    // ---- stage-with-retry of generation t into hlds[t&1] (poll IS the stage) ----
    auto stage = [&](int t) {
        const unsigned* srcs = hbuf + (size_t)(t & 1) * 32768 + (size_t)g16 * 512;
        char* dst = (char*)hlds[t & 1];
        const unsigned p32 = pat32(t);
        u32x4 c[8];
        #pragma unroll
        for (int rd = 0; rd < 8; ++rd) {
            const int gch = tid + rd * 256;            // chunk id [0,2048)
            const int row = gch >> 7, c16 = gch & 127;
            const unsigned* p = srcs + row * 512 + c16 * 4;
            asm volatile("global_load_dwordx4 %0, %1, off sc0 sc1"
                         : "=v"(c[rd]) : "v"(p) : "memory");
        }
        asm volatile("s_waitcnt vmcnt(0)" ::: "memory");   // also drains publish+history
        unsigned fm = 0u;
        #pragma unroll
        for (int rd = 0; rd < 8; ++rd) {
            const unsigned y = ((c[rd][0] ^ p32) | (c[rd][1] ^ p32) |
                                (c[rd][2] ^ p32) | (c[rd][3] ^ p32)) & SIGN32;
            if (y) fm |= 1u << rd;
        }
        while (fm) {
            #pragma unroll
            for (int rd = 0; rd < 8; ++rd) {
                if (fm & (1u << rd)) {
                    const int gch = tid + rd * 256;
                    const int row = gch >> 7, c16 = gch & 127;
                    const unsigned* p = srcs + row * 512 + c16 * 4;
                    asm volatile("global_load_dwordx4 %0, %1, off sc0 sc1"
                                 : "=v"(c[rd]) : "v"(p) : "memory");
                }
            }
            asm volatile("s_waitcnt vmcnt(0)" ::: "memory");
            #pragma unroll
            for (int rd = 0; rd < 8; ++rd) {
                if (fm & (1u << rd)) {
                    const unsigned y = ((c[rd][0] ^ p32) | (c[rd][1] ^ p32) |
                                        (c[rd][2] ^ p32) | (c[rd][3] ^ p32)) & SIGN32;
                    if (!y) fm &= ~(1u << rd);
                }
            }
        }
        #pragma unroll
        for (int rd = 0; rd < 8; ++rd) {
            const int gch = tid + rd * 256;
            const int row = gch >> 7, c16 = gch & 127;
            u32x4 s;
            s[0] = c[rd][0] & STRIP32; s[1] = c[rd][1] & STRIP32;
            s[2] = c[rd][2] & STRIP32; s[3] = c[rd][3] & STRIP32;
            *(u32x4*)(dst + row * 2048 + ((c16 ^ (row & 7)) * 16)) = s;
        }
    };

    // prologue: stage h[0], barrier
    stage(0);
    __syncthreads();

    #pragma unroll 1
    for (int t = 0; t < TT; ++t) {
        // ---- MFMA: C rows lq*4+r, col icol, K=1024 from swizzled LDS ----
        f32x4 acc[4] = {{0,0,0,0},{0,0,0,0},{0,0,0,0},{0,0,0,0}};
        const char* arow = (const char*)hlds[t & 1] + l15 * 2048;
        #pragma unroll
        for (int kc = 0; kc < 32; ++kc) {
            s16x8 a0 = *(const s16x8*)(arow + (((kc << 2 | lq) ^ (l15 & 7)) * 16));
            acc[kc & 3] = __builtin_amdgcn_mfma_f32_16x16x32_bf16(a0, wfr[kc], acc[kc & 3], 0, 0, 0);
        }

        // ---- epilogue ----
        const float phs = PH_SCALE * phv;
        const float pis = PI_SCALE * piv;
        float xn_[4], hv_[4];
        #pragma unroll
        for (int r = 0; r < 4; ++r) {
            const float rec = acc[0][r] + acc[1][r] + acc[2][r] + acc[3][r];
            float drive = 0.f;
            if (isStr) drive = (ipf[r].x + pis) * iw0 + (ipf[r].y + pis) * iw1 +
                               (ipf[r].z + pis) * iw2 + (ipf[r].w + pis) * iw3;
            const float xp = xr[r];
            const float xn = xp + DT_ * (-xp + rec + drive + inh[r]) + phs;
            const float hv = fmaxf(xn, 0.f);
            xr[r] = xn; xn_[r] = xn; hv_[r] = hv;
        }

        // ---- publish h[t+1] tagged, fire-and-forget (skip at t=TT-1: unused;
        //      also preserves replay tag-safety) ----
        if (t + 1 < TT) {
            unsigned* nxt = hbuf + (size_t)((t + 1) & 1) * 32768;
            const unsigned pn = pat32(t + 1);
            float prr[4];
            #pragma unroll
            for (int r = 0; r < 4; ++r) prr[r] = __shfl_xor(hv_[r], 1);
            if (!(l15 & 1)) {
                #pragma unroll
                for (int r = 0; r < 4; ++r) {
                    const unsigned val = (((unsigned)bf16_bits(hv_[r]) |
                                           ((unsigned)bf16_bits(prr[r]) << 16)) & STRIP32);
                    __hip_atomic_store(nxt + (size_t)(g16 + lq * 4 + r) * 512 + (icol >> 1),
                                       val | pn, __ATOMIC_RELAXED, __HIP_MEMORY_SCOPE_AGENT);
                }
            }
        }

        // ---- history stores: plain (L2-ack); their acks overlap the stage
        //      loads' L3 latency inside stage()'s first vmcnt(0) ----
        #pragma unroll
        for (int r = 0; r < 4; ++r) {
            const int bi = g16 + lq * 4 + r;
            const size_t o = ((size_t)bi * TT + t) * HH2 + icol;
            rnn_out[o] = hv_[r];
            x_out[o]   = xn_[r];
        }

        // ---- next-step input prefetch ----
        const int tn = (t + 1 < TT) ? (t + 1) : t;
        #pragma unroll
        for (int r = 0; r < 4; ++r)
            ipf[r] = *(const float4*)(inp + ((size_t)(g16 + lq * 4 + r) * TT + tn) * 4);
        phv = ph[tn]; piv = pig[tn];

        // ---- stage h[t+1] (poll+load combined), then the ONE barrier ----
        if (t + 1 < TT) stage(t + 1);
        __syncthreads();
    }
}

// ---------------- fc1: out[b,t] = dot(rnn_out[b,t,512:1024], fc1_w[512:1024]) + fc1_b ----------------
__global__ __launch_bounds__(256) void fc1_kernel(
    const float* __restrict__ rnn_out, const float* __restrict__ fc1_w,
    const float* __restrict__ fc1_b, float* __restrict__ out)
{
    const int wid = blockIdx.x * 4 + (threadIdx.x >> 6);  // [0, 64000)
    const int lane = threadIdx.x & 63;
    const float* p = rnn_out + (size_t)wid * HH2 + HH + lane * 8;
    const float* w = fc1_w + HH + lane * 8;
    f32x4 v0 = *(const f32x4*)(p);
    f32x4 v1 = *(const f32x4*)(p + 4);
    f32x4 w0 = *(const f32x4*)(w);
    f32x4 w1 = *(const f32x4*)(w + 4);
    float s = v0[0]*w0[0] + v0[1]*w0[1] + v0[2]*w0[2] + v0[3]*w0[3]
            + v1[0]*w1[0] + v1[1]*w1[1] + v1[2]*w1[2] + v1[3]*w1[3];
    #pragma unroll
    for (int off = 32; off; off >>= 1) s += __shfl_xor(s, off);
    if (lane == 0) out[wid] = s + fc1_b[0];
}

// ---------------- last-state extraction ----------------
__global__ __launch_bounds__(256) void last_kernel(
    const float* __restrict__ rnn_out, const float* __restrict__ x_out,
    float* __restrict__ hn_last, float* __restrict__ x_last)
{
    const int idx = blockIdx.x * 256 + threadIdx.x;  // [0, 65536)
    const int b = idx >> 10;
    const int i = idx & 1023;
    const size_t o = ((size_t)b * TT + (TT - 1)) * HH2 + i;
    hn_last[idx] = rnn_out[o];
    x_last[idx]  = x_out[o];
}

extern "C" void kernel_launch(void* const* d_in, const int* in_sizes, int n_in,
                              void* d_out, int out_size, void* d_ws, size_t ws_size,
                              hipStream_t stream) {
    const float* inp   = (const float*)d_in[0];   // [64,1000,4]
    const float* hn    = (const float*)d_in[1];   // [1,64,1024]
    const float* x     = (const float*)d_in[2];   // [1,64,1024]
    const float* inhib = (const float*)d_in[3];   // [64,1024]
    const float* ph    = (const float*)d_in[4];   // [1000]
    const float* pi    = (const float*)d_in[5];   // [1000]
    const float* s2s   = (const float*)d_in[6];   // [512,512]
    const float* a2a   = (const float*)d_in[7];
    const float* a2s   = (const float*)d_in[8];
    const float* s2a   = (const float*)d_in[9];
    const float* iw    = (const float*)d_in[10];  // [4,1024]
    const float* fw    = (const float*)d_in[11];  // [1,1024]
    const float* fb    = (const float*)d_in[12];  // [1]

    // Output tuple layout (floats): out | hn_last | rnn_out | x_last | x_out
    float* out     = (float*)d_out;               // 64000
    float* hn_last = out + 64000;                 // 65536
    float* rnn_out = out + 129536;                // 65,536,000
    float* x_last  = out + 65665536;              // 65536
    float* x_out   = out + 65731072;              // 65,536,000

    // Workspace: hbuf [2][64][512] u32 = 256 KB. No init needed: generation tags
    // self-disambiguate against both 0xAA poison and previous-replay residue.
    unsigned* hbuf = (unsigned*)d_ws;

    rnn_persistent<<<64, 256, 0, stream>>>(inp, hn, x, inhib, ph, pi,
                                           s2s, a2a, a2s, s2a, iw,
                                           rnn_out, x_out, hbuf);
    fc1_kernel<<<16000, 256, 0, stream>>>(rnn_out, fw, fb, out);
    last_kernel<<<256, 256, 0, stream>>>(rnn_out, x_out, hn_last, x_last);
}